// Round 11
// baseline (353.812 us; speedup 1.0000x reference)
//
#include <hip/hip_runtime.h>

#define Bg   128
#define NPG  512
#define EPGc 8192
#define Etot (Bg*EPGc)
#define DOUTc 10
#define K1c  410
#define K2c  328
#define N0c  (Bg*NPG)
#define N1c  (Bg*K1c)
#define N2c  (Bg*K2c)
#define EPSc 1e-5f

typedef __attribute__((ext_vector_type(8))) short s8v;   // 8 bf16 (4 VGPRs)
typedef __attribute__((ext_vector_type(4))) float f4v;   // mfma acc

static __device__ __forceinline__ unsigned short bf_rne(float x) {
  unsigned u = __float_as_uint(x);
  u += 0x7FFFu + ((u >> 16) & 1u);       // round-to-nearest-even
  return (unsigned short)(u >> 16);
}
static __device__ __forceinline__ float bf_f(unsigned short h) {
  return __uint_as_float(((unsigned)h) << 16);
}

// ---------------- layer-0 graph prep (+ fused W-pack & BN1 scale/shift) --------
static __global__ __launch_bounds__(512) void k_prep0(const int* __restrict__ src,
                                                      const int* __restrict__ dst,
                                                      const float* __restrict__ W1,
                                                      const float* __restrict__ W2,
                                                      const float* __restrict__ bn1g,
                                                      const float* __restrict__ bn1b,
                                                      const float* __restrict__ bn1m,
                                                      const float* __restrict__ bn1v,
                                                      unsigned short* __restrict__ pk,
                                                      float2* __restrict__ bnp,
                                                      float* __restrict__ dinv,
                                                      int* __restrict__ rp,
                                                      int2* __restrict__ e2,
                                                      float* __restrict__ pooled) {
  __shared__ int    cnt[NPG];
  __shared__ float  sdv[NPG];
  __shared__ int    srp[NPG];
  __shared__ int    sbuf[512];
  int g = blockIdx.x, tid = threadIdx.x;
  cnt[tid] = 0;
  if (tid < 128) {                       // zero pooled slices (atomic targets)
    pooled[g * 128 + tid] = 0.f;
    pooled[Bg * 128 + g * 128 + tid] = 0.f;
    pooled[2 * Bg * 128 + g * 128 + tid] = 0.f;
    // BN1 scale/shift (every block writes identical values — benign)
    float sc = bn1g[tid] / sqrtf(bn1v[tid] + EPSc);
    bnp[tid] = make_float2(sc, bn1b[tid] - bn1m[tid] * sc);
  }
  if (tid < 256) {                       // fused packW: i in [0,32768)
    int i = g * 256 + tid;
    const float* W = (i < 16384) ? W1 : W2;
    unsigned short* d = pk + ((i < 16384) ? 0 : 32768);
    int ii = i & 16383;
    int grp = ii >> 9, lane = (ii >> 3) & 63, j = ii & 7;
    int kk = grp >> 3, t = grp & 7;
    int k = kk * 32 + (lane >> 4) * 8 + j;
    int n = t * 16 + (lane & 15);
    float w = W[k * 128 + n];
    unsigned short hi = bf_rne(w);
    d[ii] = hi;
    d[16384 + ii] = bf_rne(w - bf_f(hi));
  }
  __syncthreads();
  const int* sp = src + (size_t)g * EPGc;
  const int* dp = dst + (size_t)g * EPGc;
  for (int e = tid; e < EPGc; e += 512) atomicAdd(&cnt[dp[e] - g * NPG], 1);
  __syncthreads();
  int c = cnt[tid];
  float dv = 1.0f / sqrtf(1.0f + (float)c);
  sdv[tid] = dv;
  dinv[g * NPG + tid] = dv;
  sbuf[tid] = c;
  __syncthreads();
  for (int off = 1; off < 512; off <<= 1) {
    int t = (tid >= off) ? sbuf[tid - off] : 0;
    __syncthreads();
    sbuf[tid] += t;
    __syncthreads();
  }
  srp[tid] = sbuf[tid] - c;
  rp[g * (NPG + 1) + tid] = sbuf[tid] - c;
  if (tid == 511) rp[g * (NPG + 1) + NPG] = sbuf[511];
  cnt[tid] = 0;
  __syncthreads();
  for (int e = tid; e < EPGc; e += 512) {
    int s = sp[e], d = dp[e];
    int dl = d - g * NPG;
    int pos = srp[dl] + atomicAdd(&cnt[dl], 1);
    e2[(size_t)g * EPGc + pos] =
        make_int2(s, __float_as_int(sdv[s - g * NPG] * sdv[dl]));
  }
}

// ---------------- MFMA GEMM, 512thr/128 rows (+fused graph-sum; FUSE: +poolbn) --
// Round-11: old 256thr/64row version ran 45us latency-bound (MfmaUtil 5%, occ 16%
// — 4 sequential blocks/CU each re-staging 64KB W behind a barrier). Now one
// resident round (L0: 512 blocks, L1: 410), 16 waves/CU. FUSE (layer 1): A-rows
// ARE xp1 = relu(bn(h1[perm]*tsel)) — computed inline, xp1 never materialized;
// graph-sum via 16-lane shuffle reduce (per-lane atomic fallback at graph-
// boundary tiles, since 410 % 128 != 0).
template <bool FUSE, int NROWG>
static __global__ __launch_bounds__(512) void k_gemm4(const float* __restrict__ X,
                                                      const unsigned short* __restrict__ pk,
                                                      float* __restrict__ Y,
                                                      float* __restrict__ pooledseg,
                                                      const int* __restrict__ perm,
                                                      const float* __restrict__ tsel,
                                                      const float2* __restrict__ bnp) {
  __shared__ unsigned short wl[32768];   // 64 KB: hi[16384] + lo[16384]
  int tid = threadIdx.x;
  for (int i = tid; i < 4096; i += 512) ((int4*)wl)[i] = ((const int4*)pk)[i];
  int wv = tid >> 6, lane = tid & 63;
  int q = lane >> 4, m16 = lane & 15;
  int grow0 = blockIdx.x * 128 + wv * 16;
  int row = grow0 + m16;
  int gsel = row / NROWG;
  bool uni = (grow0 / NROWG) == ((grow0 + 15) / NROWG);
  const float* xr_base;
  float tmul = 1.f;
  if (FUSE) {
    int old = perm[row];
    tmul = tsel[row];
    xr_base = X + (size_t)old * 128;
  } else {
    xr_base = X + (size_t)row * 128;
  }
  s8v ahi[4], alo[4];
#pragma unroll
  for (int kk = 0; kk < 4; ++kk) {
    const float* xr = xr_base + kk * 32 + q * 8;
    float4 a0 = *(const float4*)xr;
    float4 a1 = *(const float4*)(xr + 4);
    float av[8] = {a0.x, a0.y, a0.z, a0.w, a1.x, a1.y, a1.z, a1.w};
    if (FUSE) {
#pragma unroll
      for (int j = 0; j < 8; ++j) {
        float2 ss = bnp[kk * 32 + q * 8 + j];
        av[j] = fmaxf(ss.x * (av[j] * tmul) + ss.y, 0.f);
      }
    }
    if (pooledseg) {
      if (uni) {
#pragma unroll
        for (int j = 0; j < 8; ++j) {
          float v = av[j];
          v += __shfl_xor(v, 1, 64); v += __shfl_xor(v, 2, 64);
          v += __shfl_xor(v, 4, 64); v += __shfl_xor(v, 8, 64);
          if (m16 == 0) atomicAdd(&pooledseg[gsel * 128 + kk * 32 + q * 8 + j], v);
        }
      } else {
#pragma unroll
        for (int j = 0; j < 8; ++j)
          atomicAdd(&pooledseg[gsel * 128 + kk * 32 + q * 8 + j], av[j]);
      }
    }
    union { unsigned short u[8]; s8v v; } H, L;
#pragma unroll
    for (int j = 0; j < 8; ++j) {
      unsigned short h = bf_rne(av[j]);
      H.u[j] = h;
      L.u[j] = bf_rne(av[j] - bf_f(h));
    }
    ahi[kk] = H.v; alo[kk] = L.v;
  }
  __syncthreads();
  int orow0 = grow0 + q * 4;
#pragma unroll
  for (int t = 0; t < 8; ++t) {
    f4v acc = {0.f, 0.f, 0.f, 0.f};
#pragma unroll
    for (int kk = 0; kk < 4; ++kk) {
      s8v bhi = *(const s8v*)&wl[(kk * 8 + t) * 512 + lane * 8];
      s8v blo = *(const s8v*)&wl[16384 + (kk * 8 + t) * 512 + lane * 8];
      acc = __builtin_amdgcn_mfma_f32_16x16x32_bf16(ahi[kk], bhi, acc, 0, 0, 0);
      acc = __builtin_amdgcn_mfma_f32_16x16x32_bf16(alo[kk], bhi, acc, 0, 0, 0);
      acc = __builtin_amdgcn_mfma_f32_16x16x32_bf16(ahi[kk], blo, acc, 0, 0, 0);
    }
#pragma unroll
    for (int r = 0; r < 4; ++r)
      Y[(size_t)(orow0 + r) * 128 + t * 16 + m16] = acc[r];
  }
}

// GCN aggregation: x4 L2 gather + fused score GEMV (at its mixed-L2 roofline:
// 612 MB @ 14.2 TB/s, 97% L2 hit).
template <int NPER, int RG>
static __global__ __launch_bounds__(256) void k_agg3(const float* __restrict__ h0,
                                                     const float* __restrict__ dinv,
                                                     const float* __restrict__ bias,
                                                     const int* __restrict__ rp,
                                                     const int2* __restrict__ e2,
                                                     const float* __restrict__ sw,
                                                     float* __restrict__ h1,
                                                     float* __restrict__ spre) {
  int tid = threadIdx.x;
  int hw = tid >> 5, l = tid & 31;
  int b = blockIdx.x;
  int xcd = b & 7, slot = b >> 3;
  int g = xcd * 16 + (slot & 15);
  int rowgrp = slot >> 4;
  int li = rowgrp * 8 + hw;
  if (li >= NPER) return;
  int j = g * NPER + li;
  const int* rpg = rp + g * (NPER + 1);
  int start = rpg[li], end = rpg[li + 1];
  const int2* ep = e2 + (size_t)g * EPGc;
  float di = dinv[j];
  float sc = di * di;
  float4 acc = *(const float4*)&h0[(size_t)j * 128 + l * 4];
  float4 bb = ((const float4*)bias)[l];
  acc.x = acc.x * sc + bb.x; acc.y = acc.y * sc + bb.y;
  acc.z = acc.z * sc + bb.z; acc.w = acc.w * sc + bb.w;
  int e = start;
  for (; e + 4 <= end; e += 4) {
    int2 p0 = ep[e], p1 = ep[e + 1], p2 = ep[e + 2], p3 = ep[e + 3];
    float4 v0 = *(const float4*)&h0[(size_t)p0.x * 128 + l * 4];
    float4 v1 = *(const float4*)&h0[(size_t)p1.x * 128 + l * 4];
    float4 v2 = *(const float4*)&h0[(size_t)p2.x * 128 + l * 4];
    float4 v3 = *(const float4*)&h0[(size_t)p3.x * 128 + l * 4];
    float c0 = __int_as_float(p0.y), c1 = __int_as_float(p1.y);
    float c2 = __int_as_float(p2.y), c3 = __int_as_float(p3.y);
    acc.x += v0.x * c0 + v1.x * c1 + v2.x * c2 + v3.x * c3;
    acc.y += v0.y * c0 + v1.y * c1 + v2.y * c2 + v3.y * c3;
    acc.z += v0.z * c0 + v1.z * c1 + v2.z * c2 + v3.z * c3;
    acc.w += v0.w * c0 + v1.w * c1 + v2.w * c2 + v3.w * c3;
  }
  for (; e < end; ++e) {
    int2 pp = ep[e];
    float c = __int_as_float(pp.y);
    float4 v = *(const float4*)&h0[(size_t)pp.x * 128 + l * 4];
    acc.x += v.x * c; acc.y += v.y * c; acc.z += v.z * c; acc.w += v.w * c;
  }
  ((float4*)&h1[(size_t)j * 128])[l] = acc;
  float4 w4 = ((const float4*)sw)[l];
  float pr = acc.x * w4.x + acc.y * w4.y + acc.z * w4.z + acc.w * w4.w;
#pragma unroll
  for (int off = 16; off; off >>= 1) pr += __shfl_xor(pr, off, 64);
  if (l == 0) spre[j] = pr;
}

// ---------------- repool: score + topk + remap + edge filter + CSR rebuild ----
template <int NPER, int K>
static __global__ __launch_bounds__(512) void k_repool(const float* __restrict__ spre,
                                                       const float* __restrict__ dinv,
                                                       const float* __restrict__ sb,
                                                       const int* __restrict__ rp,
                                                       const int* __restrict__ src,
                                                       const int* __restrict__ dst,
                                                       int* __restrict__ perm,
                                                       float* __restrict__ tsel,
                                                       float* __restrict__ dinv2,
                                                       int* __restrict__ rp2,
                                                       int2* __restrict__ e2) {
  __shared__ float ss[NPER];
  __shared__ float sc[512];
  __shared__ int   sidx[512];
  __shared__ short rmp[NPER];
  __shared__ int   cnt[K];
  __shared__ float sdv[K];
  __shared__ int   srp[K];
  __shared__ int   sbuf[512];
  int g = blockIdx.x, tid = threadIdx.x;
  if (tid < NPER) { ss[tid] = spre[g * NPER + tid]; rmp[tid] = -1; }
  __syncthreads();
  if (tid < NPER) {
    const int* rpg = rp + g * (NPER + 1);
    int st = rpg[tid], en = rpg[tid + 1];
    const int2* ep = e2 + (size_t)g * EPGc;
    float di = dinv[g * NPER + tid];
    float acc = ss[tid] * di * di + sb[0];
    int e = st;
    for (; e + 4 <= en; e += 4) {
      int2 p0 = ep[e], p1 = ep[e + 1], p2 = ep[e + 2], p3 = ep[e + 3];
      acc += ss[p0.x - g * NPER] * __int_as_float(p0.y) +
             ss[p1.x - g * NPER] * __int_as_float(p1.y) +
             ss[p2.x - g * NPER] * __int_as_float(p2.y) +
             ss[p3.x - g * NPER] * __int_as_float(p3.y);
    }
    for (; e < en; ++e) { int2 pp = ep[e]; acc += ss[pp.x - g * NPER] * __int_as_float(pp.y); }
    sc[tid] = acc;
  } else {
    sc[tid] = -3.402823466e38f;
  }
  sidx[tid] = tid;
  __syncthreads();
  for (int kk = 2; kk <= 512; kk <<= 1) {
    for (int j = kk >> 1; j > 0; j >>= 1) {
      int i = tid, p = i ^ j;
      if (p > i) {
        bool up = ((i & kk) == 0);
        float si = sc[i], sp2 = sc[p];
        if (up ? (si < sp2) : (si > sp2)) {
          sc[i] = sp2; sc[p] = si;
          int t = sidx[i]; sidx[i] = sidx[p]; sidx[p] = t;
        }
      }
      __syncthreads();
    }
  }
  if (tid < K) {
    perm[g * K + tid] = g * NPER + sidx[tid];
    tsel[g * K + tid] = tanhf(sc[tid]);
    rmp[sidx[tid]] = (short)tid;
    cnt[tid] = 0;
  }
  __syncthreads();
  const int* sp = src + (size_t)g * EPGc;
  const int* dp = dst + (size_t)g * EPGc;
  for (int e = tid; e < EPGc; e += 512) {
    int s = rmp[sp[e] - g * NPER];
    int d = rmp[dp[e] - g * NPER];
    if ((s | d) >= 0) atomicAdd(&cnt[d], 1);
  }
  __syncthreads();
  int c = (tid < K) ? cnt[tid] : 0;
  if (tid < K) {
    float dv = 1.0f / sqrtf(1.0f + (float)c);
    sdv[tid] = dv;
    dinv2[g * K + tid] = dv;
  }
  sbuf[tid] = c;
  __syncthreads();
  for (int off = 1; off < 512; off <<= 1) {
    int t = (tid >= off) ? sbuf[tid - off] : 0;
    __syncthreads();
    sbuf[tid] += t;
    __syncthreads();
  }
  if (tid < K) { srp[tid] = sbuf[tid] - c; rp2[g * (K + 1) + tid] = sbuf[tid] - c; cnt[tid] = 0; }
  if (tid == 511) rp2[g * (K + 1) + K] = sbuf[511];
  __syncthreads();
  for (int e = tid; e < EPGc; e += 512) {
    int s = rmp[sp[e] - g * NPER];
    int d = rmp[dp[e] - g * NPER];
    if ((s | d) >= 0) {
      int pos = srp[d] + atomicAdd(&cnt[d], 1);
      e2[(size_t)g * EPGc + pos] = make_int2(g * K + s, __float_as_int(sdv[s] * sdv[d]));
    }
  }
}

// layer-2: score + topk + tanh (no edge rebuild)
template <int NPER, int K>
static __global__ __launch_bounds__(512) void k_topk2(const float* __restrict__ spre,
                                                      const float* __restrict__ dinv2,
                                                      const float* __restrict__ sb,
                                                      const int* __restrict__ rp2,
                                                      const int2* __restrict__ e2,
                                                      int* __restrict__ perm,
                                                      float* __restrict__ tsel) {
  __shared__ float ss[NPER];
  __shared__ float sc[512];
  __shared__ int   sidx[512];
  int g = blockIdx.x, tid = threadIdx.x;
  if (tid < NPER) ss[tid] = spre[g * NPER + tid];
  __syncthreads();
  if (tid < NPER) {
    const int* rpg = rp2 + g * (NPER + 1);
    int st = rpg[tid], en = rpg[tid + 1];
    const int2* ep = e2 + (size_t)g * EPGc;
    float di = dinv2[g * NPER + tid];
    float acc = ss[tid] * di * di + sb[0];
    int e = st;
    for (; e + 4 <= en; e += 4) {
      int2 p0 = ep[e], p1 = ep[e + 1], p2 = ep[e + 2], p3 = ep[e + 3];
      acc += ss[p0.x - g * NPER] * __int_as_float(p0.y) +
             ss[p1.x - g * NPER] * __int_as_float(p1.y) +
             ss[p2.x - g * NPER] * __int_as_float(p2.y) +
             ss[p3.x - g * NPER] * __int_as_float(p3.y);
    }
    for (; e < en; ++e) { int2 pp = ep[e]; acc += ss[pp.x - g * NPER] * __int_as_float(pp.y); }
    sc[tid] = acc;
  } else {
    sc[tid] = -3.402823466e38f;
  }
  sidx[tid] = tid;
  __syncthreads();
  for (int kk = 2; kk <= 512; kk <<= 1) {
    for (int j = kk >> 1; j > 0; j >>= 1) {
      int i = tid, p = i ^ j;
      if (p > i) {
        bool up = ((i & kk) == 0);
        float si = sc[i], sp2 = sc[p];
        if (up ? (si < sp2) : (si > sp2)) {
          sc[i] = sp2; sc[p] = si;
          int t = sidx[i]; sidx[i] = sidx[p]; sidx[p] = t;
        }
      }
      __syncthreads();
    }
  }
  if (tid < K) {
    perm[g * K + tid] = g * NPER + sidx[tid];
    tsel[g * K + tid] = tanhf(sc[tid]);
  }
}

// layer-2 poolbn (gather + BN + relu + graph-sum; no xp write)
template <int NPER, int CH>
static __global__ __launch_bounds__(128) void k_poolbn(const float* __restrict__ h,
                                                       const float* __restrict__ tsel,
                                                       const int* __restrict__ perm,
                                                       const float* __restrict__ gg,
                                                       const float* __restrict__ bb,
                                                       const float* __restrict__ mm,
                                                       const float* __restrict__ vv,
                                                       float* __restrict__ pooledseg) {
  int g = blockIdx.x / CH, cidx = blockIdx.x - g * CH;
  int f = threadIdx.x;
  const int rows = (NPER + CH - 1) / CH;
  int r0 = cidx * rows, r1 = min(NPER, r0 + rows);
  if (r0 >= r1) return;
  float G = gg[f], Bb = bb[f], Mm = mm[f];
  float inv = 1.0f / sqrtf(vv[f] + EPSc);
  float acc = 0.f;
  for (int r = r0; r < r1; ++r) {
    int j = g * NPER + r;
    int old = perm[j];
    float val = h[(size_t)old * 128 + f] * tsel[j];
    float o = fmaxf(G * (val - Mm) * inv + Bb, 0.f);
    acc += o;
  }
  atomicAdd(&pooledseg[g * 128 + f], acc);
}

static __global__ void k_final(const float* __restrict__ pooled,
                               const float* __restrict__ w0, const float* __restrict__ b0,
                               const float* __restrict__ w1, const float* __restrict__ b1,
                               const float* __restrict__ w2, const float* __restrict__ b2,
                               float* __restrict__ out) {
  int t = blockIdx.x * 256 + threadIdx.x;
  if (t >= Bg * DOUTc) return;
  int g = t / DOUTc, o = t - g * DOUTc;
  const float* p0 = pooled + g * 128;
  const float* p1 = pooled + Bg * 128 + g * 128;
  const float* p2 = pooled + 2 * Bg * 128 + g * 128;
  float acc = b0[o] + b1[o] + b2[o];
  for (int k = 0; k < 128; ++k)
    acc += p0[k] * w0[o * 128 + k] + p1[k] * w1[o * 128 + k] + p2[k] * w2[o * 128 + k];
  out[t] = acc;
}

extern "C" void kernel_launch(void* const* d_in, const int* in_sizes, int n_in,
                              void* d_out, int out_size, void* d_ws, size_t ws_size,
                              hipStream_t stream) {
  (void)in_sizes; (void)n_in; (void)out_size; (void)ws_size;
  const float* x    = (const float*)d_in[0];
  const int*   ei   = (const int*)d_in[1];
  const int*   src0 = ei;
  const int*   dst0 = ei + Etot;
  const float* c1W = (const float*)d_in[2];  const float* c1b = (const float*)d_in[3];
  const float* c2W = (const float*)d_in[4];  const float* c2b = (const float*)d_in[5];
  const float* s1W = (const float*)d_in[6];  const float* s1b = (const float*)d_in[7];
  const float* s2W = (const float*)d_in[8];  const float* s2b = (const float*)d_in[9];
  const float* bn1g = (const float*)d_in[10]; const float* bn1b = (const float*)d_in[11];
  const float* bn1m = (const float*)d_in[12]; const float* bn1v = (const float*)d_in[13];
  const float* bn2g = (const float*)d_in[14]; const float* bn2b = (const float*)d_in[15];
  const float* bn2m = (const float*)d_in[16]; const float* bn2v = (const float*)d_in[17];
  const float* l0W = (const float*)d_in[18]; const float* l0b = (const float*)d_in[19];
  const float* l1W = (const float*)d_in[20]; const float* l1b = (const float*)d_in[21];
  const float* l2W = (const float*)d_in[22]; const float* l2b = (const float*)d_in[23];
  float* out = (float*)d_out;

  char* p = (char*)d_ws;
  auto alloc = [&](size_t bytes) { char* q = p; p += (bytes + 255) & ~(size_t)255; return q; };
  float* h0    = (float*)alloc((size_t)N0c * 128 * 4);   // layer1 reuses as g1
  float* h1    = (float*)alloc((size_t)N0c * 128 * 4);   // layer1 reuses as h2
  float* dinv  = (float*)alloc((size_t)N0c * 4);
  float* dinv2 = (float*)alloc((size_t)N1c * 4);
  int*   rp    = (int*)alloc((size_t)Bg * (NPG + 1) * 4);
  int*   rp2   = (int*)alloc((size_t)Bg * (K1c + 1) * 4);
  int2*  e2    = (int2*)alloc((size_t)Etot * 8);
  float* spre  = (float*)alloc((size_t)N0c * 4);
  float* tsel  = (float*)alloc((size_t)N1c * 4);
  int*   perm  = (int*)alloc((size_t)N1c * 4);
  unsigned short* pk = (unsigned short*)alloc((size_t)65536 * 2);
  float2* bnp  = (float2*)alloc((size_t)128 * 8);
  float* pooled= (float*)alloc((size_t)3 * Bg * 128 * 4);

  dim3 b256(256), b512(512), b128(128);

  // ---------------- layer 0 ----------------
  k_prep0<<<Bg, b512, 0, stream>>>(src0, dst0, c1W, c2W, bn1g, bn1b, bn1m, bn1v,
                                   pk, bnp, dinv, rp, e2, pooled);
  k_gemm4<false, NPG><<<N0c / 128, b512, 0, stream>>>(x, pk, h0, pooled,
                                                      nullptr, nullptr, nullptr);
  k_agg3<NPG, 64><<<128 * 64, b256, 0, stream>>>(h0, dinv, c1b, rp, e2, s1W, h1, spre);
  k_repool<NPG, K1c><<<Bg, b512, 0, stream>>>(spre, dinv, s1b, rp, src0, dst0,
                                              perm, tsel, dinv2, rp2, e2);

  // ---------------- layer 1 (gemm fuses poolbn-L1; xp1 never materialized) ----
  float* g1 = h0;   // h0 dead after agg3-L0
  k_gemm4<true, K1c><<<N1c / 128, b512, 0, stream>>>(h1, pk + 32768, g1,
                                                     pooled + Bg * 128, perm, tsel, bnp);
  float* h2 = h1;   // h1 dead after gemm4-L1
  k_agg3<K1c, 52><<<128 * 52, b256, 0, stream>>>(g1, dinv2, c2b, rp2, e2, s2W, h2, spre);
  k_topk2<K1c, K2c><<<Bg, b512, 0, stream>>>(spre, dinv2, s2b, rp2, e2, perm, tsel);
  k_poolbn<K2c, 16><<<Bg * 16, b128, 0, stream>>>(h2, tsel, perm, bn2g, bn2b,
                                                  bn2m, bn2v, pooled + 2 * Bg * 128);

  // ---------------- readout ----------------
  k_final<<<(Bg * DOUTc + 255) / 256, b256, 0, stream>>>(pooled, l0W, l0b, l1W, l1b, l2W, l2b, out);
}